// Round 1
// baseline (333.532 us; speedup 1.0000x reference)
//
#include <hip/hip_runtime.h>
#include <math.h>

#define HW 512
#define IMG (HW*HW)
#define MLOG32f 3.4657359027997265f

// strict unfused fp32 to match reference per-op rounding (bin/threshold knife-edge)
__device__ __forceinline__ float grayf(float r, float g, float b) {
    float t = __fadd_rn(__fadd_rn(__fmul_rn(0.299f, r), __fmul_rn(0.587f, g)), __fmul_rn(0.114f, b));
    float s = __fmul_rn(0.5f, __fadd_rn(t, 1.0f));
    return fminf(fmaxf(s, 0.0f), 1.0f);
}

__device__ __forceinline__ float softplusf(float x) {
    return fmaxf(x, 0.0f) + log1pf(expf(-fabsf(x)));
}

// ---------------- K0: zero ws accumulators + scalar constants ----------------
__global__ void k_init(const float* __restrict__ cal_a, const float* __restrict__ cal_b,
                       const float* __restrict__ alpha_logits, const float* __restrict__ tau_p,
                       int* __restrict__ hist, float* __restrict__ expsum,
                       float* __restrict__ sc, int B) {
    int tid = threadIdx.x;
    for (int i = tid; i < B * 32; i += blockDim.x) hist[i] = 0;
    for (int i = tid; i < B; i += blockDim.x) expsum[i] = 0.0f;
    if (tid == 0) {
        float al[4];
        float m = -1e30f;
        for (int c = 0; c < 4; c++) { al[c] = alpha_logits[c]; m = fmaxf(m, al[c]); }
        float e[4]; float s = 0.0f;
        for (int c = 0; c < 4; c++) { e[c] = expf(al[c] - m); s += e[c]; }
        float bias = 0.0f;
        for (int c = 0; c < 4; c++) {
            float alpha = e[c] / s;
            sc[c] = alpha * softplusf(cal_a[c]);
            bias += alpha * cal_b[c];
        }
        sc[4] = bias;
        sc[5] = 0.2f + softplusf(tau_p[0]);
    }
}

// ---------------- K1: gray + per-image histogram ----------------
__global__ __launch_bounds__(256) void k_gray_hist(const float* __restrict__ img,
                                                   float* __restrict__ gray,
                                                   int* __restrict__ hist) {
    __shared__ int lh[32];
    int tid = threadIdx.x;
    int b = blockIdx.y;
    if (tid < 32) lh[tid] = 0;
    __syncthreads();
    const float4* rp = (const float4*)(img + (size_t)b * 3 * IMG);
    const float4* gp = (const float4*)(img + (size_t)b * 3 * IMG + IMG);
    const float4* bp = (const float4*)(img + (size_t)b * 3 * IMG + 2 * IMG);
    float4* op = (float4*)(gray + (size_t)b * IMG);
    int i = blockIdx.x * 256 + tid;            // float4 index; grid.x = IMG/1024
    float4 r = rp[i], g = gp[i], bb = bp[i];
    float4 o;
    o.x = grayf(r.x, g.x, bb.x);
    o.y = grayf(r.y, g.y, bb.y);
    o.z = grayf(r.z, g.z, bb.z);
    o.w = grayf(r.w, g.w, bb.w);
    op[i] = o;
    int b0 = min(max((int)(o.x * 32.0f), 0), 31);
    int b1 = min(max((int)(o.y * 32.0f), 0), 31);
    int b2 = min(max((int)(o.z * 32.0f), 0), 31);
    int b3 = min(max((int)(o.w * 32.0f), 0), 31);
    atomicAdd(&lh[b0], 1); atomicAdd(&lh[b1], 1);
    atomicAdd(&lh[b2], 1); atomicAdd(&lh[b3], 1);
    __syncthreads();
    if (tid < 32) atomicAdd(&hist[b * 32 + tid], lh[tid]);
}

// ---------------- K2: Otsu per image ----------------
__global__ void k_otsu(const int* __restrict__ hist, float* __restrict__ thr, int B) {
    int b = threadIdx.x;
    if (b >= B) return;
    const int* h = hist + b * 32;
    float omega[32], mu[32];
    float co = 0.0f, cm = 0.0f;
    for (int k = 0; k < 32; k++) {
        float pk = (float)h[k] * (1.0f / 262144.0f);   // (H*W+1e-6) rounds to 2^18 in f32
        float xs = (float)((double)k / 31.0);
        co += pk;
        cm += pk * xs;
        omega[k] = co; mu[k] = cm;
    }
    float mu_t = mu[31];
    float best = -1e30f; int kb = 0;
    for (int k = 0; k < 32; k++) {
        float t = mu_t * omega[k] - mu[k];
        float sb = (t * t) / (omega[k] * (1.0f - omega[k]) + 1e-8f);
        if (sb > best) { best = sb; kb = k; }   // first-max, matches jnp.argmax
    }
    thr[b] = (float)kb * 0.03125f;              // edges[k] = k/32 exact
}

// ---------------- K3: threshold + fused morphology (min3,max3,max3,min3) ----------------
__global__ __launch_bounds__(256) void k_morph(const float* __restrict__ gray,
                                               const float* __restrict__ thr,
                                               float* __restrict__ nuc) {
    __shared__ float buf0[40 * 41];
    __shared__ float buf1[40 * 41];
    __shared__ float sthr;
    int tid = threadIdx.x;
    int b = blockIdx.z;
    int x0 = blockIdx.x * 32, y0 = blockIdx.y * 32;
    if (tid == 0) sthr = thr[b];
    __syncthreads();
    const float* gb = gray + (size_t)b * IMG;
    // stage 0: nuc0; out-of-image -> +inf sentinel (neutral for min)
    for (int i = tid; i < 1600; i += 256) {
        int ly = i / 40, lx = i % 40;
        int gy = y0 + ly - 4, gx = x0 + lx - 4;
        float v = 1e30f;
        if (gy >= 0 && gy < HW && gx >= 0 && gx < HW)
            v = (gb[gy * HW + gx] <= sthr) ? 1.0f : 0.0f;
        buf0[ly * 41 + lx] = v;
    }
    __syncthreads();
    // stage 1: e = min3(nuc0), margin 3; invalid -> -inf (neutral for next max)
    for (int i = tid; i < 1600; i += 256) {
        int ly = i / 40, lx = i % 40;
        float out = -1e30f;
        int gy = y0 + ly - 4, gx = x0 + lx - 4;
        if (ly >= 1 && ly < 39 && lx >= 1 && lx < 39 && gy >= 0 && gy < HW && gx >= 0 && gx < HW) {
            float m = 1e30f;
            for (int dy = -1; dy <= 1; dy++)
                for (int dx = -1; dx <= 1; dx++)
                    m = fminf(m, buf0[(ly + dy) * 41 + lx + dx]);
            out = m;
        }
        buf1[ly * 41 + lx] = out;
    }
    __syncthreads();
    // stage 2: d = max3(e), margin 2; invalid -> -inf (next is max)
    for (int i = tid; i < 1600; i += 256) {
        int ly = i / 40, lx = i % 40;
        float out = -1e30f;
        int gy = y0 + ly - 4, gx = x0 + lx - 4;
        if (ly >= 2 && ly < 38 && lx >= 2 && lx < 38 && gy >= 0 && gy < HW && gx >= 0 && gx < HW) {
            float m = -1e30f;
            for (int dy = -1; dy <= 1; dy++)
                for (int dx = -1; dx <= 1; dx++)
                    m = fmaxf(m, buf1[(ly + dy) * 41 + lx + dx]);
            out = m;
        }
        buf0[ly * 41 + lx] = out;
    }
    __syncthreads();
    // stage 3: d2 = max3(d), margin 1; invalid -> +inf (next is min)
    for (int i = tid; i < 1600; i += 256) {
        int ly = i / 40, lx = i % 40;
        float out = 1e30f;
        int gy = y0 + ly - 4, gx = x0 + lx - 4;
        if (ly >= 3 && ly < 37 && lx >= 3 && lx < 37 && gy >= 0 && gy < HW && gx >= 0 && gx < HW) {
            float m = -1e30f;
            for (int dy = -1; dy <= 1; dy++)
                for (int dx = -1; dx <= 1; dx++)
                    m = fmaxf(m, buf0[(ly + dy) * 41 + lx + dx]);
            out = m;
        }
        buf1[ly * 41 + lx] = out;
    }
    __syncthreads();
    // stage 4: e2 = min3(d2) on output 32x32; nuc = e2 > 0.5
    for (int i = tid; i < 1024; i += 256) {
        int py = i >> 5, px = i & 31;
        int ly = py + 4, lx = px + 4;
        float m = 1e30f;
        for (int dy = -1; dy <= 1; dy++)
            for (int dx = -1; dx <= 1; dx++)
                m = fminf(m, buf1[(ly + dy) * 41 + lx + dx]);
        nuc[(size_t)b * IMG + (y0 + py) * HW + (x0 + px)] = (m > 0.5f) ? 1.0f : 0.0f;
    }
}

// ---------------- K4a: circ_var (ch1) + ent_like (ch3) from gray ----------------
__global__ __launch_bounds__(256) void k_gray_maps(const float* __restrict__ gray,
                                                   float* zmap) {
    __shared__ float gt[42 * 43];    // gray, region [-5,37)^2, OOB=0 (zero pad)
    __shared__ float st[40 * 41];    // sin, region [-4,36)^2, OOB-center=0
    __shared__ float ct[40 * 41];    // cos
    __shared__ float rs0[40 * 33];
    __shared__ float rs1[40 * 33];
    int tid = threadIdx.x, b = blockIdx.z;
    int x0 = blockIdx.x * 32, y0 = blockIdx.y * 32;
    const float* gb = gray + (size_t)b * IMG;
    for (int i = tid; i < 42 * 42; i += 256) {
        int ly = i / 42, lx = i % 42;
        int gy = y0 + ly - 5, gx = x0 + lx - 5;
        gt[ly * 43 + lx] = (gy >= 0 && gy < HW && gx >= 0 && gx < HW) ? gb[gy * HW + gx] : 0.0f;
    }
    __syncthreads();
    // sobel -> unit vector (sin(atan2(gy,gx)) = gy/r, cos = gx/r; r=0 -> (0,1))
    for (int i = tid; i < 1600; i += 256) {
        int ly = i / 40, lx = i % 40;
        int gy = y0 + ly - 4, gx = x0 + lx - 4;
        float s = 0.0f, c = 0.0f;
        if (gy >= 0 && gy < HW && gx >= 0 && gx < HW) {   // zero-pad local_sum: OOB contributes 0
            float a00 = gt[ly * 43 + lx],       a01 = gt[ly * 43 + lx + 1],       a02 = gt[ly * 43 + lx + 2];
            float a10 = gt[(ly + 1) * 43 + lx],                                   a12 = gt[(ly + 1) * 43 + lx + 2];
            float a20 = gt[(ly + 2) * 43 + lx], a21 = gt[(ly + 2) * 43 + lx + 1], a22 = gt[(ly + 2) * 43 + lx + 2];
            float gxv = (a00 - a02) + 2.0f * (a10 - a12) + (a20 - a22);
            float gyv = (a00 + 2.0f * a01 + a02) - (a20 + 2.0f * a21 + a22);
            float r2 = gxv * gxv + gyv * gyv;
            if (r2 > 0.0f) { float r = sqrtf(r2); s = gyv / r; c = gxv / r; }
            else { s = 0.0f; c = 1.0f; }   // atan2(0,0)=0
        }
        st[ly * 41 + lx] = s; ct[ly * 41 + lx] = c;
    }
    __syncthreads();
    for (int i = tid; i < 40 * 32; i += 256) {
        int ly = i / 32, lx = i % 32;
        float ss = 0.0f, cs = 0.0f;
        for (int dx = 0; dx < 9; dx++) { ss += st[ly * 41 + lx + dx]; cs += ct[ly * 41 + lx + dx]; }
        rs0[ly * 33 + lx] = ss; rs1[ly * 33 + lx] = cs;
    }
    __syncthreads();
    float z1v[4];
    for (int k = 0; k < 4; k++) {
        int j = tid + k * 256; int py = j >> 5, px = j & 31;
        float ss = 0.0f, cs = 0.0f;
        for (int dy = 0; dy < 9; dy++) { ss += rs0[(py + dy) * 33 + px]; cs += rs1[(py + dy) * 33 + px]; }
        int gy = y0 + py, gx = x0 + px;
        float cnty = (float)(min(gy + 4, HW - 1) - max(gy - 4, 0) + 1);
        float cntx = (float)(min(gx + 4, HW - 1) - max(gx - 4, 0) + 1);
        float den = cnty * cntx + 1e-6f;
        float ms = ss / den, mc = cs / den;
        z1v[k] = 1.0f - sqrtf(ms * ms + mc * mc + 1e-6f);
    }
    __syncthreads();
    // reuse rs0/rs1 for gray / gray^2 row sums (rows [-4,36) = gt row ly+1, cols lx+1..lx+9)
    for (int i = tid; i < 40 * 32; i += 256) {
        int ly = i / 32, lx = i % 32;
        float gs = 0.0f, g2s = 0.0f;
        for (int dx = 1; dx <= 9; dx++) { float v = gt[(ly + 1) * 43 + lx + dx]; gs += v; g2s += v * v; }
        rs0[ly * 33 + lx] = gs; rs1[ly * 33 + lx] = g2s;
    }
    __syncthreads();
    float* z1p = zmap + ((size_t)b * 4 + 1) * IMG;
    float* z3p = zmap + ((size_t)b * 4 + 3) * IMG;
    for (int k = 0; k < 4; k++) {
        int j = tid + k * 256; int py = j >> 5, px = j & 31;
        float gs = 0.0f, g2s = 0.0f;
        for (int dy = 0; dy < 9; dy++) { gs += rs0[(py + dy) * 33 + px]; g2s += rs1[(py + dy) * 33 + px]; }
        int gy = y0 + py, gx = x0 + px;
        float cnty = (float)(min(gy + 4, HW - 1) - max(gy - 4, 0) + 1);
        float cntx = (float)(min(gx + 4, HW - 1) - max(gx - 4, 0) + 1);
        float den = cnty * cntx + 1e-6f;
        float g1 = gs / den, g2 = g2s / den;
        z1p[gy * HW + gx] = z1v[k];
        z3p[gy * HW + gx] = log1pf(fmaxf(g2 - g1 * g1, 0.0f));
    }
}

// ---------------- K4b: roughness (ch0) + nc (ch2) + E + expsum ----------------
__global__ __launch_bounds__(256) void k_nuc_maps(const float* __restrict__ nuc,
                                                  float* zmap,
                                                  float* __restrict__ Eout,
                                                  const float* __restrict__ sc,
                                                  float* __restrict__ expsum) {
    __shared__ float nt[50 * 51];   // nuc, region [-9,41)^2, OOB=0
    __shared__ float bt[36 * 37];   // boundary, region [-2,34)^2, OOB=0
    __shared__ float rb[36 * 33];   // 5-wide row sums of boundary
    __shared__ float hm[50 * 41];   // horizontal 11-max, rows [-9,41), col centers [-4,36)
    __shared__ float cl[40 * 41];   // cell (maxpool11), region [-4,36)^2, OOB-center=0
    __shared__ float rn[40 * 33];   // 9-wide row sums of nuc
    __shared__ float rc[40 * 33];   // 9-wide row sums of cell
    __shared__ float red[256];
    int tid = threadIdx.x, b = blockIdx.z;
    int x0 = blockIdx.x * 32, y0 = blockIdx.y * 32;
    const float* nb = nuc + (size_t)b * IMG;
    for (int i = tid; i < 50 * 50; i += 256) {
        int ly = i / 50, lx = i % 50;
        int gy = y0 + ly - 9, gx = x0 + lx - 9;
        nt[ly * 51 + lx] = (gy >= 0 && gy < HW && gx >= 0 && gx < HW) ? nb[gy * HW + gx] : 0.0f;
    }
    __syncthreads();
    // boundary = max(nuc - min3(nuc), 0); min pads +inf (skip OOB), boundary OOB=0
    for (int i = tid; i < 36 * 36; i += 256) {
        int ly = i / 36, lx = i % 36;
        int gy = y0 + ly - 2, gx = x0 + lx - 2;
        float v = 0.0f;
        if (gy >= 0 && gy < HW && gx >= 0 && gx < HW) {
            int ny = ly + 7, nx = lx + 7;
            float er = 2.0f;
            for (int dy = -1; dy <= 1; dy++)
                for (int dx = -1; dx <= 1; dx++) {
                    int qy = gy + dy, qx = gx + dx;
                    float q = (qy >= 0 && qy < HW && qx >= 0 && qx < HW) ? nt[(ny + dy) * 51 + nx + dx] : 2.0f;
                    er = fminf(er, q);
                }
            v = fmaxf(nt[ny * 51 + nx] - er, 0.0f);
        }
        bt[ly * 37 + lx] = v;
    }
    __syncthreads();
    for (int i = tid; i < 36 * 32; i += 256) {
        int ly = i / 32, lx = i % 32;
        float s = 0.0f;
        for (int dx = 0; dx < 5; dx++) s += bt[ly * 37 + lx + dx];
        rb[ly * 33 + lx] = s;
    }
    __syncthreads();
    float roughv[4];
    for (int k = 0; k < 4; k++) {
        int j = tid + k * 256; int py = j >> 5, px = j & 31;
        float den = 1e-6f;
        for (int dy = 0; dy < 5; dy++) den += rb[(py + dy) * 33 + px];
        int ny = py + 9, nx = px + 9;
        float c = nt[ny * 51 + nx];
        float lap = fabsf(nt[(ny - 1) * 51 + nx] + nt[(ny + 1) * 51 + nx] +
                          nt[ny * 51 + nx - 1] + nt[ny * 51 + nx + 1] - 4.0f * c);
        float bnd = bt[(py + 2) * 37 + px + 2];
        roughv[k] = lap * bnd / den;
    }
    __syncthreads();
    // cell = maxpool11(nuc), separable; nuc>=0 so OOB=0 works for the max
    for (int i = tid; i < 50 * 40; i += 256) {
        int ly = i / 40, lx = i % 40;
        float m = 0.0f;
        for (int dx = 0; dx < 11; dx++) m = fmaxf(m, nt[ly * 51 + lx + dx]);
        hm[ly * 41 + lx] = m;
    }
    __syncthreads();
    for (int i = tid; i < 1600; i += 256) {
        int ly = i / 40, lx = i % 40;
        int gy = y0 + ly - 4, gx = x0 + lx - 4;
        float m = 0.0f;
        if (gy >= 0 && gy < HW && gx >= 0 && gx < HW) {   // OOB centers must be 0 for zero-pad 9x9 sum
            for (int dy = 0; dy < 11; dy++) m = fmaxf(m, hm[(ly + dy) * 41 + lx]);
        }
        cl[ly * 41 + lx] = m;
    }
    __syncthreads();
    for (int i = tid; i < 40 * 32; i += 256) {
        int ly = i / 32, lx = i % 32;
        float s1 = 0.0f, s2 = 0.0f;
        for (int dx = 0; dx < 9; dx++) {
            s1 += nt[(ly + 5) * 51 + lx + 5 + dx];
            s2 += cl[ly * 41 + lx + dx];
        }
        rn[ly * 33 + lx] = s1; rc[ly * 33 + lx] = s2;
    }
    __syncthreads();
    float w0 = sc[0], w1 = sc[1], w2 = sc[2], w3 = sc[3], bias = sc[4], tau = sc[5];
    const float* z1p = zmap + ((size_t)b * 4 + 1) * IMG;
    const float* z3p = zmap + ((size_t)b * 4 + 3) * IMG;
    float* z0p = zmap + ((size_t)b * 4 + 0) * IMG;
    float* z2p = zmap + ((size_t)b * 4 + 2) * IMG;
    float* Ep = Eout + (size_t)b * IMG;
    float acc = 0.0f;
    for (int k = 0; k < 4; k++) {
        int j = tid + k * 256; int py = j >> 5, px = j & 31;
        float An = 0.0f, Ac = 0.0f;
        for (int dy = 0; dy < 9; dy++) { An += rn[(py + dy) * 33 + px]; Ac += rc[(py + dy) * 33 + px]; }
        float z2 = An / fmaxf(Ac - An, 1.0f);
        int gy = y0 + py, gx = x0 + px;
        float z1 = z1p[gy * HW + gx], z3 = z3p[gy * HW + gx];
        float z0s = log1pf(fmaxf(roughv[k], 0.0f));
        float z1s = fminf(fmaxf(z1, 0.0f), 1.0f);
        float z2s = log1pf(fmaxf(z2, 0.0f));
        float z3s = fminf(fmaxf(z3, 0.0f), MLOG32f);
        float E = w0 * z0s + w1 * z1s + w2 * z2s + w3 * z3s + bias;
        z0p[gy * HW + gx] = roughv[k];
        z2p[gy * HW + gx] = z2;
        Ep[gy * HW + gx] = E;
        acc += expf(-E / tau);
    }
    red[tid] = acc;
    __syncthreads();
    for (int s = 128; s > 0; s >>= 1) {
        if (tid < s) red[tid] += red[tid + s];
        __syncthreads();
    }
    if (tid == 0) atomicAdd(&expsum[b], red[0]);
}

// ---------------- K5: A = exp(-E/tau) / S ----------------
__global__ __launch_bounds__(256) void k_softmaxA(const float* __restrict__ E,
                                                  float* __restrict__ A,
                                                  const float* __restrict__ sc,
                                                  const float* __restrict__ expsum) {
    int b = blockIdx.y;
    int i = blockIdx.x * 256 + threadIdx.x;   // float4 index
    float tau = sc[5], S = expsum[b];
    const float4* Ep = (const float4*)(E + (size_t)b * IMG);
    float4* Ap = (float4*)(A + (size_t)b * IMG);
    float4 e = Ep[i];
    float4 o;
    o.x = expf(-e.x / tau) / S;
    o.y = expf(-e.y / tau) / S;
    o.z = expf(-e.z / tau) / S;
    o.w = expf(-e.w / tau) / S;
    Ap[i] = o;
}

extern "C" void kernel_launch(void* const* d_in, const int* in_sizes, int n_in,
                              void* d_out, int out_size, void* d_ws, size_t ws_size,
                              hipStream_t stream) {
    const float* img   = (const float*)d_in[0];
    const float* cal_a = (const float*)d_in[1];
    const float* cal_b = (const float*)d_in[2];
    const float* alpha = (const float*)d_in[3];
    const float* tau_p = (const float*)d_in[4];
    int B = in_sizes[0] / (3 * IMG);

    float* out  = (float*)d_out;
    float* A    = out;                          // (B,1,H,W)
    float* zmap = out + (size_t)B * IMG;        // (B,4,H,W)
    float* nuc  = out + (size_t)B * IMG * 5;    // (B,1,H,W)
    float* E    = out + (size_t)B * IMG * 6;    // (B,1,H,W)
    float* gray = A;                            // A region doubles as gray scratch (A written last)

    int*   hist   = (int*)d_ws;                 // B*32 ints
    float* thr    = (float*)d_ws + B * 32;      // B floats
    float* sc     = thr + B;                    // 8 floats: w0..3, bias, tau
    float* expsum = sc + 8;                     // B floats

    k_init<<<1, 256, 0, stream>>>(cal_a, cal_b, alpha, tau_p, hist, expsum, sc, B);
    k_gray_hist<<<dim3(IMG / 1024, B), 256, 0, stream>>>(img, gray, hist);
    k_otsu<<<1, 64, 0, stream>>>(hist, thr, B);
    dim3 tg(HW / 32, HW / 32, B);
    k_morph<<<tg, 256, 0, stream>>>(gray, thr, nuc);
    k_gray_maps<<<tg, 256, 0, stream>>>(gray, zmap);
    k_nuc_maps<<<tg, 256, 0, stream>>>(nuc, zmap, E, sc, expsum);
    k_softmaxA<<<dim3(IMG / 1024, B), 256, 0, stream>>>(E, A, sc, expsum);
}

// Round 2
// 287.558 us; speedup vs baseline: 1.1599x; 1.1599x over previous
//
#include <hip/hip_runtime.h>
#include <math.h>
#include <stdint.h>

#define HW 512
#define IMG (HW*HW)
#define MLOG32f 3.4657359027997265f

// strict unfused fp32 to match reference per-op rounding (bin/threshold knife-edge)
__device__ __forceinline__ float grayf(float r, float g, float b) {
    float t = __fadd_rn(__fadd_rn(__fmul_rn(0.299f, r), __fmul_rn(0.587f, g)), __fmul_rn(0.114f, b));
    float s = __fmul_rn(0.5f, __fadd_rn(t, 1.0f));
    return fminf(fmaxf(s, 0.0f), 1.0f);
}

__device__ __forceinline__ float softplusf(float x) {
    return fmaxf(x, 0.0f) + log1pf(expf(-fabsf(x)));
}

// bits [lo, hi), hi < 64
__device__ __forceinline__ uint64_t kmask(int lo, int hi) {
    return (1ull << hi) - (1ull << lo);
}

// ---------------- K0: zero ws accumulators + scalar constants ----------------
__global__ void k_init(const float* __restrict__ cal_a, const float* __restrict__ cal_b,
                       const float* __restrict__ alpha_logits, const float* __restrict__ tau_p,
                       int* __restrict__ hist, float* __restrict__ expsum,
                       float* __restrict__ sc, int B) {
    int tid = threadIdx.x;
    for (int i = tid; i < B * 32; i += blockDim.x) hist[i] = 0;
    for (int i = tid; i < B; i += blockDim.x) expsum[i] = 0.0f;
    if (tid == 0) {
        float al[4];
        float m = -1e30f;
        for (int c = 0; c < 4; c++) { al[c] = alpha_logits[c]; m = fmaxf(m, al[c]); }
        float e[4]; float s = 0.0f;
        for (int c = 0; c < 4; c++) { e[c] = expf(al[c] - m); s += e[c]; }
        float bias = 0.0f;
        for (int c = 0; c < 4; c++) {
            float alpha = e[c] / s;
            sc[c] = alpha * softplusf(cal_a[c]);
            bias += alpha * cal_b[c];
        }
        sc[4] = bias;
        sc[5] = 0.2f + softplusf(tau_p[0]);
    }
}

// ---------------- K1: gray + per-image histogram ----------------
__global__ __launch_bounds__(256) void k_gray_hist(const float* __restrict__ img,
                                                   float* __restrict__ gray,
                                                   int* __restrict__ hist) {
    __shared__ int lh[32];
    int tid = threadIdx.x;
    int b = blockIdx.y;
    if (tid < 32) lh[tid] = 0;
    __syncthreads();
    const float4* rp = (const float4*)(img + (size_t)b * 3 * IMG);
    const float4* gp = (const float4*)(img + (size_t)b * 3 * IMG + IMG);
    const float4* bp = (const float4*)(img + (size_t)b * 3 * IMG + 2 * IMG);
    float4* op = (float4*)(gray + (size_t)b * IMG);
    int i = blockIdx.x * 256 + tid;            // float4 index; grid.x = IMG/1024
    float4 r = rp[i], g = gp[i], bb = bp[i];
    float4 o;
    o.x = grayf(r.x, g.x, bb.x);
    o.y = grayf(r.y, g.y, bb.y);
    o.z = grayf(r.z, g.z, bb.z);
    o.w = grayf(r.w, g.w, bb.w);
    op[i] = o;
    int b0 = min(max((int)(o.x * 32.0f), 0), 31);
    int b1 = min(max((int)(o.y * 32.0f), 0), 31);
    int b2 = min(max((int)(o.z * 32.0f), 0), 31);
    int b3 = min(max((int)(o.w * 32.0f), 0), 31);
    atomicAdd(&lh[b0], 1); atomicAdd(&lh[b1], 1);
    atomicAdd(&lh[b2], 1); atomicAdd(&lh[b3], 1);
    __syncthreads();
    if (tid < 32) atomicAdd(&hist[b * 32 + tid], lh[tid]);
}

// ---------------- K2: Otsu per image ----------------
__global__ void k_otsu(const int* __restrict__ hist, float* __restrict__ thr, int B) {
    int b = threadIdx.x;
    if (b >= B) return;
    const int* h = hist + b * 32;
    float omega[32], mu[32];
    float co = 0.0f, cm = 0.0f;
    for (int k = 0; k < 32; k++) {
        float pk = (float)h[k] * (1.0f / 262144.0f);   // (H*W+1e-6) rounds to 2^18 in f32
        float xs = (float)((double)k / 31.0);
        co += pk;
        cm += pk * xs;
        omega[k] = co; mu[k] = cm;
    }
    float mu_t = mu[31];
    float best = -1e30f; int kb = 0;
    for (int k = 0; k < 32; k++) {
        float t = mu_t * omega[k] - mu[k];
        float sb = (t * t) / (omega[k] * (1.0f - omega[k]) + 1e-8f);
        if (sb > best) { best = sb; kb = k; }   // first-max, matches jnp.argmax
    }
    thr[b] = (float)kb * 0.03125f;              // edges[k] = k/32 exact
}

// ---------------- K2b: threshold gray -> packed bits (bit j of word w = px 32w+j) ----
__global__ __launch_bounds__(256) void k_thresh(const float* __restrict__ gray,
                                                const float* __restrict__ thr,
                                                uint32_t* __restrict__ packed) {
    int b = blockIdx.y;
    int i = blockIdx.x * 256 + threadIdx.x;    // pixel index within image
    float t = thr[b];
    float v = gray[(size_t)b * IMG + i];
    unsigned long long m = __ballot(v <= t);
    if ((threadIdx.x & 63) == 0)
        *(uint64_t*)&packed[(size_t)b * 8192 + (i >> 5)] = m;
}

// ---------------- K3: bitwise morphology (erode,dilate,dilate,erode) ----------------
// bit k of a row word <-> x = x0 - 4 + k, k in [0,40)
__global__ __launch_bounds__(256) void k_morph(const uint32_t* __restrict__ p0,
                                               float* __restrict__ nuc,
                                               uint32_t* __restrict__ pn) {
    __shared__ uint64_t s0[40], s1[40];
    int tid = threadIdx.x, b = blockIdx.z;
    int x0 = blockIdx.x * 32, y0 = blockIdx.y * 32;
    int w0 = x0 >> 5;
    const uint32_t* pb = p0 + (size_t)b * 8192;
    int xlo = (x0 == 0) ? 4 : 0;
    int xhi = (x0 == 480) ? 36 : 40;
    uint64_t mwin = kmask(xlo, xhi);           // in-image bits (horizontal)

    if (tid < 40) {
        int y = y0 - 4 + tid;
        uint64_t v = 0;
        if ((unsigned)y < (unsigned)HW) {
            const uint32_t* rowp = pb + y * 16;
            uint64_t wm = (w0 > 0)  ? rowp[w0 - 1] : 0;
            uint64_t wc = rowp[w0];
            uint64_t wp = (w0 < 15) ? rowp[w0 + 1] : 0;
            v = ((wm >> 28) | (wc << 4) | (wp << 36)) & kmask(0, 40);
        }
        s0[tid] = v;   // raw nuc0, OOB bits = 0
    }
    __syncthreads();
    // stage e = erode3(nuc0), rows [1,39), bits valid [1,39); pad=1
    if (tid >= 1 && tid < 39) {
        uint64_t e = ~0ull;
        for (int dq = -1; dq <= 1; dq++) {
            int q = tid + dq;
            int y = y0 - 4 + q;
            uint64_t m = ((unsigned)y < (unsigned)HW) ? mwin : 0;
            uint64_t v = s0[q] | ~m;
            e &= v & (v << 1) & (v >> 1);
        }
        s1[tid] = e;
    }
    __syncthreads();
    // stage d1 = dilate3(e), rows [2,38); pad=0
    if (tid >= 2 && tid < 38) {
        uint64_t d = 0;
        uint64_t me = kmask(1, 39);
        for (int dq = -1; dq <= 1; dq++) {
            int q = tid + dq;
            int y = y0 - 4 + q;
            uint64_t m = ((unsigned)y < (unsigned)HW) ? (mwin & me) : 0;
            uint64_t v = s1[q] & m;
            d |= v | (v << 1) | (v >> 1);
        }
        s0[tid] = d;
    }
    __syncthreads();
    // stage d2 = dilate3(d1), rows [3,37); pad=0
    if (tid >= 3 && tid < 37) {
        uint64_t d = 0;
        uint64_t me = kmask(2, 38);
        for (int dq = -1; dq <= 1; dq++) {
            int q = tid + dq;
            int y = y0 - 4 + q;
            uint64_t m = ((unsigned)y < (unsigned)HW) ? (mwin & me) : 0;
            uint64_t v = s0[q] & m;
            d |= v | (v << 1) | (v >> 1);
        }
        s1[tid] = d;
    }
    __syncthreads();
    // stage e2 = erode3(d2), rows [4,36); pad=1
    if (tid >= 4 && tid < 36) {
        uint64_t e = ~0ull;
        uint64_t me = kmask(3, 37);
        for (int dq = -1; dq <= 1; dq++) {
            int q = tid + dq;
            int y = y0 - 4 + q;
            uint64_t m = ((unsigned)y < (unsigned)HW) ? (mwin & me) : 0;
            uint64_t v = s1[q] | ~m;
            e &= v & (v << 1) & (v >> 1);
        }
        s0[tid] = e;
    }
    __syncthreads();
    if (tid < 32) {
        int y = y0 + tid;
        pn[(size_t)b * 8192 + y * 16 + w0] = (uint32_t)(s0[tid + 4] >> 4);
    }
    float* nb = nuc + (size_t)b * IMG;
    for (int k = 0; k < 4; k++) {
        int i = tid + k * 256;
        int py = i >> 5, px = i & 31;
        nb[(size_t)(y0 + py) * HW + x0 + px] = (float)((s0[py + 4] >> (px + 4)) & 1);
    }
}

// ---------------- K4a: circ_var (ch1) + ent_like (ch3) from gray (unchanged) ----------------
__global__ __launch_bounds__(256) void k_gray_maps(const float* __restrict__ gray,
                                                   float* zmap) {
    __shared__ float gt[42 * 43];
    __shared__ float st[40 * 41];
    __shared__ float ct[40 * 41];
    __shared__ float rs0[40 * 33];
    __shared__ float rs1[40 * 33];
    int tid = threadIdx.x, b = blockIdx.z;
    int x0 = blockIdx.x * 32, y0 = blockIdx.y * 32;
    const float* gb = gray + (size_t)b * IMG;
    for (int i = tid; i < 42 * 42; i += 256) {
        int ly = i / 42, lx = i % 42;
        int gy = y0 + ly - 5, gx = x0 + lx - 5;
        gt[ly * 43 + lx] = (gy >= 0 && gy < HW && gx >= 0 && gx < HW) ? gb[gy * HW + gx] : 0.0f;
    }
    __syncthreads();
    for (int i = tid; i < 1600; i += 256) {
        int ly = i / 40, lx = i % 40;
        int gy = y0 + ly - 4, gx = x0 + lx - 4;
        float s = 0.0f, c = 0.0f;
        if (gy >= 0 && gy < HW && gx >= 0 && gx < HW) {
            float a00 = gt[ly * 43 + lx],       a01 = gt[ly * 43 + lx + 1],       a02 = gt[ly * 43 + lx + 2];
            float a10 = gt[(ly + 1) * 43 + lx],                                   a12 = gt[(ly + 1) * 43 + lx + 2];
            float a20 = gt[(ly + 2) * 43 + lx], a21 = gt[(ly + 2) * 43 + lx + 1], a22 = gt[(ly + 2) * 43 + lx + 2];
            float gxv = (a00 - a02) + 2.0f * (a10 - a12) + (a20 - a22);
            float gyv = (a00 + 2.0f * a01 + a02) - (a20 + 2.0f * a21 + a22);
            float r2 = gxv * gxv + gyv * gyv;
            if (r2 > 0.0f) { float r = sqrtf(r2); s = gyv / r; c = gxv / r; }
            else { s = 0.0f; c = 1.0f; }
        }
        st[ly * 41 + lx] = s; ct[ly * 41 + lx] = c;
    }
    __syncthreads();
    for (int i = tid; i < 40 * 32; i += 256) {
        int ly = i / 32, lx = i % 32;
        float ss = 0.0f, cs = 0.0f;
        for (int dx = 0; dx < 9; dx++) { ss += st[ly * 41 + lx + dx]; cs += ct[ly * 41 + lx + dx]; }
        rs0[ly * 33 + lx] = ss; rs1[ly * 33 + lx] = cs;
    }
    __syncthreads();
    float z1v[4];
    for (int k = 0; k < 4; k++) {
        int j = tid + k * 256; int py = j >> 5, px = j & 31;
        float ss = 0.0f, cs = 0.0f;
        for (int dy = 0; dy < 9; dy++) { ss += rs0[(py + dy) * 33 + px]; cs += rs1[(py + dy) * 33 + px]; }
        int gy = y0 + py, gx = x0 + px;
        float cnty = (float)(min(gy + 4, HW - 1) - max(gy - 4, 0) + 1);
        float cntx = (float)(min(gx + 4, HW - 1) - max(gx - 4, 0) + 1);
        float den = cnty * cntx + 1e-6f;
        float ms = ss / den, mc = cs / den;
        z1v[k] = 1.0f - sqrtf(ms * ms + mc * mc + 1e-6f);
    }
    __syncthreads();
    for (int i = tid; i < 40 * 32; i += 256) {
        int ly = i / 32, lx = i % 32;
        float gs = 0.0f, g2s = 0.0f;
        for (int dx = 1; dx <= 9; dx++) { float v = gt[(ly + 1) * 43 + lx + dx]; gs += v; g2s += v * v; }
        rs0[ly * 33 + lx] = gs; rs1[ly * 33 + lx] = g2s;
    }
    __syncthreads();
    float* z1p = zmap + ((size_t)b * 4 + 1) * IMG;
    float* z3p = zmap + ((size_t)b * 4 + 3) * IMG;
    for (int k = 0; k < 4; k++) {
        int j = tid + k * 256; int py = j >> 5, px = j & 31;
        float gs = 0.0f, g2s = 0.0f;
        for (int dy = 0; dy < 9; dy++) { gs += rs0[(py + dy) * 33 + px]; g2s += rs1[(py + dy) * 33 + px]; }
        int gy = y0 + py, gx = x0 + px;
        float cnty = (float)(min(gy + 4, HW - 1) - max(gy - 4, 0) + 1);
        float cntx = (float)(min(gx + 4, HW - 1) - max(gx - 4, 0) + 1);
        float den = cnty * cntx + 1e-6f;
        float g1 = gs / den, g2 = g2s / den;
        z1p[gy * HW + gx] = z1v[k];
        z3p[gy * HW + gx] = log1pf(fmaxf(g2 - g1 * g1, 0.0f));
    }
}

// ---------------- K4b: bit-domain roughness (ch0) + nc (ch2) + E + expsum ----------------
// bit k of nrow <-> x = x0 - 9 + k, k in [0,50)
__global__ __launch_bounds__(256) void k_nuc_maps(const uint32_t* __restrict__ pn,
                                                  float* zmap,
                                                  float* __restrict__ Eout,
                                                  const float* __restrict__ sc,
                                                  float* __restrict__ expsum) {
    __shared__ uint64_t nrow[50];   // nuc bits, rows y0-9+r
    __shared__ uint64_t ehr[50];    // horizontal erode of padded nuc rows
    __shared__ uint64_t dilh[50];   // horizontal dilate-5 of nuc rows
    __shared__ uint64_t bnd[36];    // boundary bits, rows y0-2+rr
    __shared__ uint64_t cell[40];   // cell bits, rows y0-4+rr
    __shared__ int rs_n[40][32];    // 9-window row sums of nuc -> col prefix
    __shared__ int rs_c[40][32];    // 9-window row sums of cell -> col prefix
    __shared__ int rs_b[36][32];    // 5-window row sums of boundary -> col prefix
    __shared__ float red[256];
    int tid = threadIdx.x, b = blockIdx.z;
    int x0 = blockIdx.x * 32, y0 = blockIdx.y * 32;
    int w0 = x0 >> 5;
    const uint32_t* pb = pn + (size_t)b * 8192;
    int xlo = (x0 == 0) ? 9 : 0;
    int xhi = (x0 == 480) ? 41 : 50;
    uint64_t mwin = kmask(xlo, xhi);

    if (tid < 50) {
        int y = y0 - 9 + tid;
        uint64_t v = 0;
        if ((unsigned)y < (unsigned)HW) {
            const uint32_t* rowp = pb + y * 16;
            uint64_t wm = (w0 > 0)  ? rowp[w0 - 1] : 0;
            uint64_t wc = rowp[w0];
            uint64_t wp = (w0 < 15) ? rowp[w0 + 1] : 0;
            v = ((wm >> 23) | (wc << 9) | (wp << 41)) & kmask(0, 50);
        }
        nrow[tid] = v;
    }
    __syncthreads();
    if (tid < 50) {
        uint64_t v = nrow[tid];
        uint64_t d = v | (v << 1) | (v >> 1);
        d = d | (d << 2) | (d >> 2);
        d = d | (d << 2) | (d >> 2);           // radius-5 horizontal dilate
        dilh[tid] = d;
    }
    if (tid >= 6 && tid < 44) {
        int y = y0 - 9 + tid;
        uint64_t m = ((unsigned)y < (unsigned)HW) ? mwin : 0;
        uint64_t v = nrow[tid] | ~m;           // erosion pad = 1
        ehr[tid] = v & (v << 1) & (v >> 1);
    }
    __syncthreads();
    if (tid < 36) {
        int r = tid + 7;
        uint64_t er = ehr[r - 1] & ehr[r] & ehr[r + 1];
        bnd[tid] = nrow[r] & ~er;              // boundary = nuc & ~erode(nuc)
    }
    if (tid < 40) {
        int r = tid + 5;
        int y = y0 - 4 + tid;
        uint64_t c = 0;
        for (int d = -5; d <= 5; d++) c |= dilh[r + d];
        uint64_t m = ((unsigned)y < (unsigned)HW) ? mwin : 0;
        cell[tid] = c & m;                     // clear dilation spill into OOB px
    }
    __syncthreads();
    for (int i = tid; i < 40 * 32; i += 256) {
        int rr = i >> 5, p = i & 31;
        rs_n[rr][p] = __popcll((nrow[rr + 5] >> (p + 5)) & 0x1FFull);
        rs_c[rr][p] = __popcll((cell[rr]     >> (p + 5)) & 0x1FFull);
    }
    for (int i = tid; i < 36 * 32; i += 256) {
        int rr = i >> 5, p = i & 31;
        rs_b[rr][p] = __popcll((bnd[rr] >> (p + 7)) & 0x1Full);
    }
    __syncthreads();
    if (tid < 96) {                            // in-place column prefix sums
        int p = tid & 31, a = tid >> 5;
        if (a == 0)      { int s = 0; for (int rr = 0; rr < 40; rr++) { s += rs_n[rr][p]; rs_n[rr][p] = s; } }
        else if (a == 1) { int s = 0; for (int rr = 0; rr < 40; rr++) { s += rs_c[rr][p]; rs_c[rr][p] = s; } }
        else             { int s = 0; for (int rr = 0; rr < 36; rr++) { s += rs_b[rr][p]; rs_b[rr][p] = s; } }
    }
    __syncthreads();

    float w0f = sc[0], w1f = sc[1], w2f = sc[2], w3f = sc[3], bias = sc[4], tau = sc[5];
    const float* z1p = zmap + ((size_t)b * 4 + 1) * IMG;
    const float* z3p = zmap + ((size_t)b * 4 + 3) * IMG;
    float* z0p = zmap + ((size_t)b * 4 + 0) * IMG;
    float* z2p = zmap + ((size_t)b * 4 + 2) * IMG;
    float* Ep = Eout + (size_t)b * IMG;
    float acc = 0.0f;
    for (int k = 0; k < 4; k++) {
        int j = tid + k * 256; int py = j >> 5, p = j & 31;
        int An = rs_n[py + 8][p] - (py ? rs_n[py - 1][p] : 0);
        int Ac = rs_c[py + 8][p] - (py ? rs_c[py - 1][p] : 0);
        int db = rs_b[py + 4][p] - (py ? rs_b[py - 1][p] : 0);
        int r = py + 9, kk = p + 9;
        uint64_t rowc = nrow[r];
        int c   = (int)((rowc >> kk) & 1);
        int nb4 = (int)((nrow[r - 1] >> kk) & 1) + (int)((nrow[r + 1] >> kk) & 1)
                + (int)((rowc >> (kk - 1)) & 1) + (int)((rowc >> (kk + 1)) & 1);
        int lap = nb4 - 4 * c; lap = lap < 0 ? -lap : lap;
        int bc  = (int)((bnd[py + 2] >> kk) & 1);
        float den = (float)db + 1e-6f;
        float rough = (float)(lap * bc) / den;
        float z2 = (float)An / fmaxf((float)(Ac - An), 1.0f);
        int gy = y0 + py, gx = x0 + p;
        float z1 = z1p[gy * HW + gx], z3 = z3p[gy * HW + gx];
        float z0s = log1pf(fmaxf(rough, 0.0f));
        float z1s = fminf(fmaxf(z1, 0.0f), 1.0f);
        float z2s = log1pf(fmaxf(z2, 0.0f));
        float z3s = fminf(fmaxf(z3, 0.0f), MLOG32f);
        float E = w0f * z0s + w1f * z1s + w2f * z2s + w3f * z3s + bias;
        z0p[gy * HW + gx] = rough;
        z2p[gy * HW + gx] = z2;
        Ep[gy * HW + gx] = E;
        acc += expf(-E / tau);
    }
    red[tid] = acc;
    __syncthreads();
    for (int s = 128; s > 0; s >>= 1) {
        if (tid < s) red[tid] += red[tid + s];
        __syncthreads();
    }
    if (tid == 0) atomicAdd(&expsum[b], red[0]);
}

// ---------------- K5: A = exp(-E/tau) / S ----------------
__global__ __launch_bounds__(256) void k_softmaxA(const float* __restrict__ E,
                                                  float* __restrict__ A,
                                                  const float* __restrict__ sc,
                                                  const float* __restrict__ expsum) {
    int b = blockIdx.y;
    int i = blockIdx.x * 256 + threadIdx.x;
    float tau = sc[5], S = expsum[b];
    const float4* Ep = (const float4*)(E + (size_t)b * IMG);
    float4* Ap = (float4*)(A + (size_t)b * IMG);
    float4 e = Ep[i];
    float4 o;
    o.x = expf(-e.x / tau) / S;
    o.y = expf(-e.y / tau) / S;
    o.z = expf(-e.z / tau) / S;
    o.w = expf(-e.w / tau) / S;
    Ap[i] = o;
}

extern "C" void kernel_launch(void* const* d_in, const int* in_sizes, int n_in,
                              void* d_out, int out_size, void* d_ws, size_t ws_size,
                              hipStream_t stream) {
    const float* img   = (const float*)d_in[0];
    const float* cal_a = (const float*)d_in[1];
    const float* cal_b = (const float*)d_in[2];
    const float* alpha = (const float*)d_in[3];
    const float* tau_p = (const float*)d_in[4];
    int B = in_sizes[0] / (3 * IMG);

    float* out  = (float*)d_out;
    float* A    = out;                          // (B,1,H,W)
    float* zmap = out + (size_t)B * IMG;        // (B,4,H,W)
    float* nuc  = out + (size_t)B * IMG * 5;    // (B,1,H,W)
    float* E    = out + (size_t)B * IMG * 6;    // (B,1,H,W)
    float* gray = A;                            // A region doubles as gray scratch

    // ws layout (needs ~1.05 MB): hist | thr | sc | expsum | packed0 | packedN
    int*      hist    = (int*)d_ws;                      // B*32 ints
    float*    thr     = (float*)d_ws + B * 32;           // B floats
    float*    sc      = thr + B;                         // 8 floats
    float*    expsum  = sc + 8;                          // B floats
    uint32_t* packed0 = (uint32_t*)d_ws + 1024;          // B*8192 words (nuc0 bits)
    uint32_t* packedN = packed0 + (size_t)B * 8192;      // B*8192 words (nuc bits)

    k_init<<<1, 256, 0, stream>>>(cal_a, cal_b, alpha, tau_p, hist, expsum, sc, B);
    k_gray_hist<<<dim3(IMG / 1024, B), 256, 0, stream>>>(img, gray, hist);
    k_otsu<<<1, 64, 0, stream>>>(hist, thr, B);
    k_thresh<<<dim3(IMG / 256, B), 256, 0, stream>>>(gray, thr, packed0);
    dim3 tg(HW / 32, HW / 32, B);
    k_morph<<<tg, 256, 0, stream>>>(packed0, nuc, packedN);
    k_gray_maps<<<tg, 256, 0, stream>>>(gray, zmap);
    k_nuc_maps<<<tg, 256, 0, stream>>>(packedN, zmap, E, sc, expsum);
    k_softmaxA<<<dim3(IMG / 1024, B), 256, 0, stream>>>(E, A, sc, expsum);
}

// Round 3
// 257.473 us; speedup vs baseline: 1.2954x; 1.1168x over previous
//
#include <hip/hip_runtime.h>
#include <math.h>
#include <stdint.h>

#define HW 512
#define IMG (HW*HW)
#define MLOG32f 3.4657359027997265f

// strict unfused fp32 to match reference per-op rounding (bin/threshold knife-edge)
__device__ __forceinline__ float grayf(float r, float g, float b) {
    float t = __fadd_rn(__fadd_rn(__fmul_rn(0.299f, r), __fmul_rn(0.587f, g)), __fmul_rn(0.114f, b));
    float s = __fmul_rn(0.5f, __fadd_rn(t, 1.0f));
    return fminf(fmaxf(s, 0.0f), 1.0f);
}

__device__ __forceinline__ float softplusf(float x) {
    return fmaxf(x, 0.0f) + log1pf(expf(-fabsf(x)));
}

__device__ __forceinline__ float frcp(float x)  { return __builtin_amdgcn_rcpf(x); }
__device__ __forceinline__ float frsq(float x)  { return __builtin_amdgcn_rsqf(x); }
__device__ __forceinline__ float flog1p(float x){ return __logf(1.0f + x); }

// bits [lo, hi), hi < 64
__device__ __forceinline__ uint64_t kmask(int lo, int hi) {
    return (1ull << hi) - (1ull << lo);
}

// ---------------- K0: zero ws accumulators + scalar constants ----------------
__global__ void k_init(const float* __restrict__ cal_a, const float* __restrict__ cal_b,
                       const float* __restrict__ alpha_logits, const float* __restrict__ tau_p,
                       int* __restrict__ hist, float* __restrict__ expsum,
                       float* __restrict__ sc, int B) {
    int tid = threadIdx.x;
    for (int i = tid; i < B * 32; i += blockDim.x) hist[i] = 0;
    for (int i = tid; i < B; i += blockDim.x) expsum[i] = 0.0f;
    if (tid == 0) {
        float al[4];
        float m = -1e30f;
        for (int c = 0; c < 4; c++) { al[c] = alpha_logits[c]; m = fmaxf(m, al[c]); }
        float e[4]; float s = 0.0f;
        for (int c = 0; c < 4; c++) { e[c] = expf(al[c] - m); s += e[c]; }
        float bias = 0.0f;
        for (int c = 0; c < 4; c++) {
            float alpha = e[c] / s;
            sc[c] = alpha * softplusf(cal_a[c]);
            bias += alpha * cal_b[c];
        }
        sc[4] = bias;
        float tau = 0.2f + softplusf(tau_p[0]);
        sc[5] = tau;
        sc[6] = -1.0f / tau;   // exponent scale
    }
}

// ---------------- K1: gray + per-image histogram ----------------
__global__ __launch_bounds__(256) void k_gray_hist(const float* __restrict__ img,
                                                   float* __restrict__ gray,
                                                   int* __restrict__ hist) {
    __shared__ int lh[32];
    int tid = threadIdx.x;
    int b = blockIdx.y;
    if (tid < 32) lh[tid] = 0;
    __syncthreads();
    const float4* rp = (const float4*)(img + (size_t)b * 3 * IMG);
    const float4* gp = (const float4*)(img + (size_t)b * 3 * IMG + IMG);
    const float4* bp = (const float4*)(img + (size_t)b * 3 * IMG + 2 * IMG);
    float4* op = (float4*)(gray + (size_t)b * IMG);
    int i = blockIdx.x * 256 + tid;            // float4 index; grid.x = IMG/1024
    float4 r = rp[i], g = gp[i], bb = bp[i];
    float4 o;
    o.x = grayf(r.x, g.x, bb.x);
    o.y = grayf(r.y, g.y, bb.y);
    o.z = grayf(r.z, g.z, bb.z);
    o.w = grayf(r.w, g.w, bb.w);
    op[i] = o;
    int b0 = min(max((int)(o.x * 32.0f), 0), 31);
    int b1 = min(max((int)(o.y * 32.0f), 0), 31);
    int b2 = min(max((int)(o.z * 32.0f), 0), 31);
    int b3 = min(max((int)(o.w * 32.0f), 0), 31);
    atomicAdd(&lh[b0], 1); atomicAdd(&lh[b1], 1);
    atomicAdd(&lh[b2], 1); atomicAdd(&lh[b3], 1);
    __syncthreads();
    if (tid < 32) atomicAdd(&hist[b * 32 + tid], lh[tid]);
}

// ---------------- K2: Otsu per image ----------------
__global__ void k_otsu(const int* __restrict__ hist, float* __restrict__ thr, int B) {
    int b = threadIdx.x;
    if (b >= B) return;
    const int* h = hist + b * 32;
    float omega[32], mu[32];
    float co = 0.0f, cm = 0.0f;
    for (int k = 0; k < 32; k++) {
        float pk = (float)h[k] * (1.0f / 262144.0f);   // (H*W+1e-6) rounds to 2^18 in f32
        float xs = (float)((double)k / 31.0);
        co += pk;
        cm += pk * xs;
        omega[k] = co; mu[k] = cm;
    }
    float mu_t = mu[31];
    float best = -1e30f; int kb = 0;
    for (int k = 0; k < 32; k++) {
        float t = mu_t * omega[k] - mu[k];
        float sb = (t * t) / (omega[k] * (1.0f - omega[k]) + 1e-8f);
        if (sb > best) { best = sb; kb = k; }   // first-max, matches jnp.argmax
    }
    thr[b] = (float)kb * 0.03125f;              // edges[k] = k/32 exact
}

// ---------------- K2b: threshold gray -> packed bits (bit j of word w = px 32w+j) ----
__global__ __launch_bounds__(256) void k_thresh(const float* __restrict__ gray,
                                                const float* __restrict__ thr,
                                                uint32_t* __restrict__ packed) {
    int b = blockIdx.y;
    int i = blockIdx.x * 256 + threadIdx.x;    // pixel index within image
    float t = thr[b];
    float v = gray[(size_t)b * IMG + i];
    unsigned long long m = __ballot(v <= t);
    if ((threadIdx.x & 63) == 0)
        *(uint64_t*)&packed[(size_t)b * 8192 + (i >> 5)] = m;
}

// ---------------- K3: bitwise morphology (erode,dilate,dilate,erode) ----------------
// bit k of a row word <-> x = x0 - 4 + k, k in [0,40)
__global__ __launch_bounds__(256) void k_morph(const uint32_t* __restrict__ p0,
                                               uint32_t* __restrict__ pn) {
    __shared__ uint64_t s0[40], s1[40];
    int tid = threadIdx.x, b = blockIdx.z;
    int x0 = blockIdx.x * 32, y0 = blockIdx.y * 32;
    int w0 = x0 >> 5;
    const uint32_t* pb = p0 + (size_t)b * 8192;
    int xlo = (x0 == 0) ? 4 : 0;
    int xhi = (x0 == 480) ? 36 : 40;
    uint64_t mwin = kmask(xlo, xhi);           // in-image bits (horizontal)

    if (tid < 40) {
        int y = y0 - 4 + tid;
        uint64_t v = 0;
        if ((unsigned)y < (unsigned)HW) {
            const uint32_t* rowp = pb + y * 16;
            uint64_t wm = (w0 > 0)  ? rowp[w0 - 1] : 0;
            uint64_t wc = rowp[w0];
            uint64_t wp = (w0 < 15) ? rowp[w0 + 1] : 0;
            v = ((wm >> 28) | (wc << 4) | (wp << 36)) & kmask(0, 40);
        }
        s0[tid] = v;   // raw nuc0, OOB bits = 0
    }
    __syncthreads();
    if (tid >= 1 && tid < 39) {
        uint64_t e = ~0ull;
        for (int dq = -1; dq <= 1; dq++) {
            int q = tid + dq;
            int y = y0 - 4 + q;
            uint64_t m = ((unsigned)y < (unsigned)HW) ? mwin : 0;
            uint64_t v = s0[q] | ~m;
            e &= v & (v << 1) & (v >> 1);
        }
        s1[tid] = e;
    }
    __syncthreads();
    if (tid >= 2 && tid < 38) {
        uint64_t d = 0;
        uint64_t me = kmask(1, 39);
        for (int dq = -1; dq <= 1; dq++) {
            int q = tid + dq;
            int y = y0 - 4 + q;
            uint64_t m = ((unsigned)y < (unsigned)HW) ? (mwin & me) : 0;
            uint64_t v = s1[q] & m;
            d |= v | (v << 1) | (v >> 1);
        }
        s0[tid] = d;
    }
    __syncthreads();
    if (tid >= 3 && tid < 37) {
        uint64_t d = 0;
        uint64_t me = kmask(2, 38);
        for (int dq = -1; dq <= 1; dq++) {
            int q = tid + dq;
            int y = y0 - 4 + q;
            uint64_t m = ((unsigned)y < (unsigned)HW) ? (mwin & me) : 0;
            uint64_t v = s0[q] & m;
            d |= v | (v << 1) | (v >> 1);
        }
        s1[tid] = d;
    }
    __syncthreads();
    if (tid >= 4 && tid < 36) {
        uint64_t e = ~0ull;
        uint64_t me = kmask(3, 37);
        for (int dq = -1; dq <= 1; dq++) {
            int q = tid + dq;
            int y = y0 - 4 + q;
            uint64_t m = ((unsigned)y < (unsigned)HW) ? (mwin & me) : 0;
            uint64_t v = s1[q] | ~m;
            e &= v & (v << 1) & (v >> 1);
        }
        s0[tid] = e;
    }
    __syncthreads();
    if (tid < 32) {
        int y = y0 + tid;
        pn[(size_t)b * 8192 + y * 16 + w0] = (uint32_t)(s0[tid + 4] >> 4);
    }
}

// ---------------- K4: fused concept maps + E + expsum ----------------
// float LDS tiles (gt/st/ct/rs0/rs1) die before the int prefix arrays are
// born, so both live in one aliased buffer: peak LDS ~33 KB -> 4 blocks/CU.
__global__ __launch_bounds__(256) void k_maps(const float* __restrict__ gray,
                                              const uint32_t* __restrict__ pn,
                                              float* __restrict__ zmap,
                                              float* __restrict__ nucf,
                                              float* __restrict__ Eout,
                                              const float* __restrict__ sc,
                                              float* __restrict__ expsum) {
    __shared__ __align__(16) char smem[30912];
    __shared__ uint64_t nrow[50], ehr[50], dilh[50], bnd[36], cell[40];
    __shared__ float red[4];
    float* gt  = (float*)smem;             // 42*43 = 7224 B
    float* st  = (float*)(smem + 7232);    // 40*41 = 6560 B
    float* ct  = (float*)(smem + 13792);   // 40*41
    float* rs0 = (float*)(smem + 20352);   // 40*33 = 5280 B
    float* rs1 = (float*)(smem + 25632);   // 40*33
    int* rs_n = (int*)smem;                // 40*32 ints (aliases gt, dead by then)
    int* rs_c = (int*)(smem + 5120);       // 40*32
    int* rs_b = (int*)(smem + 10240);      // 36*32

    int tid = threadIdx.x, b = blockIdx.z;
    int x0 = blockIdx.x * 32, y0 = blockIdx.y * 32;
    int w0 = x0 >> 5;
    const float* gb = gray + (size_t)b * IMG;
    const uint32_t* pb = pn + (size_t)b * 8192;
    int xlo = (x0 == 0) ? 9 : 0;
    int xhi = (x0 == 480) ? 41 : 50;
    uint64_t mwin = kmask(xlo, xhi);

    // ---- loads: gray tile (halo 5) + nuc bit rows (halo 9) ----
    for (int i = tid; i < 42 * 42; i += 256) {
        int ly = i / 42, lx = i % 42;
        int gy = y0 + ly - 5, gx = x0 + lx - 5;
        gt[ly * 43 + lx] = (gy >= 0 && gy < HW && gx >= 0 && gx < HW) ? gb[gy * HW + gx] : 0.0f;
    }
    if (tid < 50) {
        int y = y0 - 9 + tid;
        uint64_t v = 0;
        if ((unsigned)y < (unsigned)HW) {
            const uint32_t* rowp = pb + y * 16;
            uint64_t wm = (w0 > 0)  ? rowp[w0 - 1] : 0;
            uint64_t wc = rowp[w0];
            uint64_t wp = (w0 < 15) ? rowp[w0 + 1] : 0;
            v = ((wm >> 23) | (wc << 9) | (wp << 41)) & kmask(0, 50);
        }
        nrow[tid] = v;
    }
    __syncthreads();

    // ---- bit phase 1: horizontal dilate-5 + horizontal erode ----
    if (tid < 50) {
        uint64_t v = nrow[tid];
        uint64_t d = v | (v << 1) | (v >> 1);
        d = d | (d << 2) | (d >> 2);
        d = d | (d << 2) | (d >> 2);           // radius-5 horizontal dilate
        dilh[tid] = d;
    }
    if (tid >= 6 && tid < 44) {
        int y = y0 - 9 + tid;
        uint64_t m = ((unsigned)y < (unsigned)HW) ? mwin : 0;
        uint64_t v = nrow[tid] | ~m;           // erosion pad = 1
        ehr[tid] = v & (v << 1) & (v >> 1);
    }
    // ---- sobel -> unit vectors (all 256 threads, overlaps bit work) ----
    for (int i = tid; i < 1600; i += 256) {
        int ly = i / 40, lx = i % 40;
        int gy = y0 + ly - 4, gx = x0 + lx - 4;
        float s = 0.0f, c = 0.0f;
        if (gy >= 0 && gy < HW && gx >= 0 && gx < HW) {
            float a00 = gt[ly * 43 + lx],       a01 = gt[ly * 43 + lx + 1],       a02 = gt[ly * 43 + lx + 2];
            float a10 = gt[(ly + 1) * 43 + lx],                                   a12 = gt[(ly + 1) * 43 + lx + 2];
            float a20 = gt[(ly + 2) * 43 + lx], a21 = gt[(ly + 2) * 43 + lx + 1], a22 = gt[(ly + 2) * 43 + lx + 2];
            float gxv = (a00 - a02) + 2.0f * (a10 - a12) + (a20 - a22);
            float gyv = (a00 + 2.0f * a01 + a02) - (a20 + 2.0f * a21 + a22);
            float r2 = gxv * gxv + gyv * gyv;
            if (r2 > 0.0f) { float ir = frsq(r2); s = gyv * ir; c = gxv * ir; }
            else { s = 0.0f; c = 1.0f; }       // atan2(0,0)=0
        }
        st[ly * 41 + lx] = s; ct[ly * 41 + lx] = c;
    }
    __syncthreads();

    // ---- bit phase 2: boundary + cell; sin/cos 9-wide row sums ----
    if (tid < 36) {
        int r = tid + 7;
        uint64_t er = ehr[r - 1] & ehr[r] & ehr[r + 1];
        bnd[tid] = nrow[r] & ~er;              // boundary = nuc & ~erode(nuc)
    }
    if (tid < 40) {
        int r = tid + 5;
        int y = y0 - 4 + tid;
        uint64_t c = 0;
        for (int d = -5; d <= 5; d++) c |= dilh[r + d];
        uint64_t m = ((unsigned)y < (unsigned)HW) ? mwin : 0;
        cell[tid] = c & m;
    }
    for (int i = tid; i < 40 * 32; i += 256) {
        int ly = i >> 5, lx = i & 31;
        float ss = 0.0f, cs = 0.0f;
        for (int dx = 0; dx < 9; dx++) { ss += st[ly * 41 + lx + dx]; cs += ct[ly * 41 + lx + dx]; }
        rs0[ly * 33 + lx] = ss; rs1[ly * 33 + lx] = cs;
    }
    __syncthreads();

    // ---- z1 (circ_var) into registers ----
    float z1v[4];
    for (int k = 0; k < 4; k++) {
        int j = tid + k * 256; int py = j >> 5, px = j & 31;
        float ss = 0.0f, cs = 0.0f;
        for (int dy = 0; dy < 9; dy++) { ss += rs0[(py + dy) * 33 + px]; cs += rs1[(py + dy) * 33 + px]; }
        int gy = y0 + py, gx = x0 + px;
        float cnty = (float)(min(gy + 4, HW - 1) - max(gy - 4, 0) + 1);
        float cntx = (float)(min(gx + 4, HW - 1) - max(gx - 4, 0) + 1);
        float iden = frcp(cnty * cntx + 1e-6f);
        float ms = ss * iden, mc = cs * iden;
        z1v[k] = 1.0f - sqrtf(ms * ms + mc * mc + 1e-6f);
    }
    __syncthreads();
    // ---- gray / gray^2 row sums (reuse rs0/rs1) ----
    for (int i = tid; i < 40 * 32; i += 256) {
        int ly = i >> 5, lx = i & 31;
        float gs = 0.0f, g2s = 0.0f;
        for (int dx = 1; dx <= 9; dx++) { float v = gt[(ly + 1) * 43 + lx + dx]; gs += v; g2s += v * v; }
        rs0[ly * 33 + lx] = gs; rs1[ly * 33 + lx] = g2s;
    }
    __syncthreads();
    // ---- z3 (ent_like) into registers ----
    float z3v[4];
    for (int k = 0; k < 4; k++) {
        int j = tid + k * 256; int py = j >> 5, px = j & 31;
        float gs = 0.0f, g2s = 0.0f;
        for (int dy = 0; dy < 9; dy++) { gs += rs0[(py + dy) * 33 + px]; g2s += rs1[(py + dy) * 33 + px]; }
        int gy = y0 + py, gx = x0 + px;
        float cnty = (float)(min(gy + 4, HW - 1) - max(gy - 4, 0) + 1);
        float cntx = (float)(min(gx + 4, HW - 1) - max(gx - 4, 0) + 1);
        float iden = frcp(cnty * cntx + 1e-6f);
        float g1 = gs * iden, g2 = g2s * iden;
        z3v[k] = flog1p(fmaxf(g2 - g1 * g1, 0.0f));
    }
    __syncthreads();   // all float LDS dead; int arrays may now alias

    // ---- popcount row windows ----
    for (int i = tid; i < 40 * 32; i += 256) {
        int rr = i >> 5, p = i & 31;
        rs_n[rr * 32 + p] = __popcll((nrow[rr + 5] >> (p + 5)) & 0x1FFull);
        rs_c[rr * 32 + p] = __popcll((cell[rr]     >> (p + 5)) & 0x1FFull);
    }
    for (int i = tid; i < 36 * 32; i += 256) {
        int rr = i >> 5, p = i & 31;
        rs_b[rr * 32 + p] = __popcll((bnd[rr] >> (p + 7)) & 0x1Full);
    }
    __syncthreads();
    if (tid < 96) {                            // in-place column prefix sums
        int p = tid & 31, a = tid >> 5;
        if (a == 0)      { int s = 0; for (int rr = 0; rr < 40; rr++) { s += rs_n[rr * 32 + p]; rs_n[rr * 32 + p] = s; } }
        else if (a == 1) { int s = 0; for (int rr = 0; rr < 40; rr++) { s += rs_c[rr * 32 + p]; rs_c[rr * 32 + p] = s; } }
        else             { int s = 0; for (int rr = 0; rr < 36; rr++) { s += rs_b[rr * 32 + p]; rs_b[rr * 32 + p] = s; } }
    }
    __syncthreads();

    // ---- epilogue: all z maps + nuc + E + expf sum ----
    float w0f = sc[0], w1f = sc[1], w2f = sc[2], w3f = sc[3], bias = sc[4], ntau = sc[6];
    float* z0p = zmap + ((size_t)b * 4 + 0) * IMG;
    float* z1p = zmap + ((size_t)b * 4 + 1) * IMG;
    float* z2p = zmap + ((size_t)b * 4 + 2) * IMG;
    float* z3p = zmap + ((size_t)b * 4 + 3) * IMG;
    float* Ep  = Eout + (size_t)b * IMG;
    float* np  = nucf + (size_t)b * IMG;
    float acc = 0.0f;
    for (int k = 0; k < 4; k++) {
        int j = tid + k * 256; int py = j >> 5, p = j & 31;
        int An = rs_n[(py + 8) * 32 + p] - (py ? rs_n[(py - 1) * 32 + p] : 0);
        int Ac = rs_c[(py + 8) * 32 + p] - (py ? rs_c[(py - 1) * 32 + p] : 0);
        int db = rs_b[(py + 4) * 32 + p] - (py ? rs_b[(py - 1) * 32 + p] : 0);
        int r = py + 9, kk = p + 9;
        uint64_t rowc = nrow[r];
        int cbit = (int)((rowc >> kk) & 1);
        int nb4  = (int)((nrow[r - 1] >> kk) & 1) + (int)((nrow[r + 1] >> kk) & 1)
                 + (int)((rowc >> (kk - 1)) & 1) + (int)((rowc >> (kk + 1)) & 1);
        int lap = nb4 - 4 * cbit; lap = lap < 0 ? -lap : lap;
        int bc  = (int)((bnd[py + 2] >> kk) & 1);
        float rough = (float)(lap * bc) * frcp((float)db + 1e-6f);
        float z2 = (float)An * frcp(fmaxf((float)(Ac - An), 1.0f));
        float z0s = flog1p(fmaxf(rough, 0.0f));
        float z1s = fminf(fmaxf(z1v[k], 0.0f), 1.0f);
        float z2s = flog1p(fmaxf(z2, 0.0f));
        float z3s = fminf(fmaxf(z3v[k], 0.0f), MLOG32f);
        float E = w0f * z0s + w1f * z1s + w2f * z2s + w3f * z3s + bias;
        int gy = y0 + py, gx = x0 + p;
        size_t o = (size_t)gy * HW + gx;
        z0p[o] = rough;
        z1p[o] = z1v[k];
        z2p[o] = z2;
        z3p[o] = z3v[k];
        Ep[o]  = E;
        np[o]  = (float)cbit;
        acc += __expf(E * ntau);
    }
    for (int off = 32; off > 0; off >>= 1) acc += __shfl_down(acc, off, 64);
    if ((tid & 63) == 0) red[tid >> 6] = acc;
    __syncthreads();
    if (tid == 0) atomicAdd(&expsum[b], red[0] + red[1] + red[2] + red[3]);
}

// ---------------- K5: A = exp(-E/tau) / S ----------------
__global__ __launch_bounds__(256) void k_softmaxA(const float* __restrict__ E,
                                                  float* __restrict__ A,
                                                  const float* __restrict__ sc,
                                                  const float* __restrict__ expsum) {
    int b = blockIdx.y;
    int i = blockIdx.x * 256 + threadIdx.x;
    float ntau = sc[6];
    float invS = 1.0f / expsum[b];
    const float4* Ep = (const float4*)(E + (size_t)b * IMG);
    float4* Ap = (float4*)(A + (size_t)b * IMG);
    float4 e = Ep[i];
    float4 o;
    o.x = __expf(e.x * ntau) * invS;
    o.y = __expf(e.y * ntau) * invS;
    o.z = __expf(e.z * ntau) * invS;
    o.w = __expf(e.w * ntau) * invS;
    Ap[i] = o;
}

extern "C" void kernel_launch(void* const* d_in, const int* in_sizes, int n_in,
                              void* d_out, int out_size, void* d_ws, size_t ws_size,
                              hipStream_t stream) {
    const float* img   = (const float*)d_in[0];
    const float* cal_a = (const float*)d_in[1];
    const float* cal_b = (const float*)d_in[2];
    const float* alpha = (const float*)d_in[3];
    const float* tau_p = (const float*)d_in[4];
    int B = in_sizes[0] / (3 * IMG);

    float* out  = (float*)d_out;
    float* A    = out;                          // (B,1,H,W)
    float* zmap = out + (size_t)B * IMG;        // (B,4,H,W)
    float* nuc  = out + (size_t)B * IMG * 5;    // (B,1,H,W)
    float* E    = out + (size_t)B * IMG * 6;    // (B,1,H,W)
    float* gray = A;                            // A region doubles as gray scratch

    // ws layout (~1.05 MB): hist | thr | sc | expsum | packed0 | packedN
    int*      hist    = (int*)d_ws;                      // B*32 ints
    float*    thr     = (float*)d_ws + B * 32;           // B floats
    float*    sc      = thr + B;                         // 8 floats
    float*    expsum  = sc + 8;                          // B floats
    uint32_t* packed0 = (uint32_t*)d_ws + 1024;          // B*8192 words (nuc0 bits)
    uint32_t* packedN = packed0 + (size_t)B * 8192;      // B*8192 words (nuc bits)

    k_init<<<1, 256, 0, stream>>>(cal_a, cal_b, alpha, tau_p, hist, expsum, sc, B);
    k_gray_hist<<<dim3(IMG / 1024, B), 256, 0, stream>>>(img, gray, hist);
    k_otsu<<<1, 64, 0, stream>>>(hist, thr, B);
    k_thresh<<<dim3(IMG / 256, B), 256, 0, stream>>>(gray, thr, packed0);
    dim3 tg(HW / 32, HW / 32, B);
    k_morph<<<tg, 256, 0, stream>>>(packed0, packedN);
    k_maps<<<tg, 256, 0, stream>>>(gray, packedN, zmap, nuc, E, sc, expsum);
    k_softmaxA<<<dim3(IMG / 1024, B), 256, 0, stream>>>(E, A, sc, expsum);
}

// Round 4
// 247.784 us; speedup vs baseline: 1.3461x; 1.0391x over previous
//
#include <hip/hip_runtime.h>
#include <math.h>
#include <stdint.h>

#define HW 512
#define IMG (HW*HW)
#define MLOG32f 3.4657359027997265f

// strict unfused fp32 to match reference per-op rounding (bin/threshold knife-edge)
__device__ __forceinline__ float grayf(float r, float g, float b) {
    float t = __fadd_rn(__fadd_rn(__fmul_rn(0.299f, r), __fmul_rn(0.587f, g)), __fmul_rn(0.114f, b));
    float s = __fmul_rn(0.5f, __fadd_rn(t, 1.0f));
    return fminf(fmaxf(s, 0.0f), 1.0f);
}

__device__ __forceinline__ float softplusf(float x) {
    return fmaxf(x, 0.0f) + log1pf(expf(-fabsf(x)));
}

__device__ __forceinline__ float frcp(float x)  { return __builtin_amdgcn_rcpf(x); }
__device__ __forceinline__ float frsq(float x)  { return __builtin_amdgcn_rsqf(x); }
__device__ __forceinline__ float flog1p(float x){ return __logf(1.0f + x); }

__device__ __forceinline__ uint64_t kmask(int lo, int hi) {
    return (1ull << hi) - (1ull << lo);
}

// ---------------- K1: gray + per-image histogram (ballot-based, no atomic serialization) ----
__global__ __launch_bounds__(256) void k_gray_hist(const float* __restrict__ img,
                                                   float* __restrict__ gray,
                                                   int* __restrict__ hist) {
    __shared__ int lh[32];
    int tid = threadIdx.x;
    int b = blockIdx.y;
    if (tid < 32) lh[tid] = 0;
    __syncthreads();
    const float4* rp = (const float4*)(img + (size_t)b * 3 * IMG);
    const float4* gp = (const float4*)(img + (size_t)b * 3 * IMG + IMG);
    const float4* bp = (const float4*)(img + (size_t)b * 3 * IMG + 2 * IMG);
    float4* op = (float4*)(gray + (size_t)b * IMG);
    int i = blockIdx.x * 256 + tid;            // float4 index; grid.x = IMG/1024
    float4 r = rp[i], g = gp[i], bb = bp[i];
    float4 o;
    o.x = grayf(r.x, g.x, bb.x);
    o.y = grayf(r.y, g.y, bb.y);
    o.z = grayf(r.z, g.z, bb.z);
    o.w = grayf(r.w, g.w, bb.w);
    op[i] = o;
    int idx[4];
    idx[0] = min(max((int)(o.x * 32.0f), 0), 31);
    idx[1] = min(max((int)(o.y * 32.0f), 0), 31);
    idx[2] = min(max((int)(o.z * 32.0f), 0), 31);
    idx[3] = min(max((int)(o.w * 32.0f), 0), 31);
    int lane = tid & 63;
    int bin = lane & 31;
    int cnt = 0;
    #pragma unroll
    for (int e = 0; e < 4; e++) {
        int v = idx[e];
        unsigned long long m0 = __ballot((v & 1)  != 0);
        unsigned long long m1 = __ballot((v & 2)  != 0);
        unsigned long long m2 = __ballot((v & 4)  != 0);
        unsigned long long m3 = __ballot((v & 8)  != 0);
        unsigned long long m4 = __ballot((v & 16) != 0);
        unsigned long long mm = (bin & 1)  ? m0 : ~m0;
        mm &= (bin & 2)  ? m1 : ~m1;
        mm &= (bin & 4)  ? m2 : ~m2;
        mm &= (bin & 8)  ? m3 : ~m3;
        mm &= (bin & 16) ? m4 : ~m4;
        cnt += __popcll(mm);
    }
    if (lane < 32) atomicAdd(&lh[bin], cnt);   // 32 distinct banks: conflict-free
    __syncthreads();
    if (tid < 32) atomicAdd(&hist[b * 32 + tid], lh[tid]);
}

// ---------------- K2: Otsu per image + scalar constants (merged) ----------------
__global__ void k_otsu_sc(const int* __restrict__ hist,
                          const float* __restrict__ cal_a, const float* __restrict__ cal_b,
                          const float* __restrict__ alpha_logits, const float* __restrict__ tau_p,
                          float* __restrict__ thr, float* __restrict__ sc, int B) {
    int tid = threadIdx.x;
    if (tid < B) {
        const int* h = hist + tid * 32;
        float omega[32], mu[32];
        float co = 0.0f, cm = 0.0f;
        for (int k = 0; k < 32; k++) {
            float pk = (float)h[k] * (1.0f / 262144.0f);   // (H*W+1e-6) rounds to 2^18 in f32
            float xs = (float)((double)k / 31.0);
            co += pk;
            cm += pk * xs;
            omega[k] = co; mu[k] = cm;
        }
        float mu_t = mu[31];
        float best = -1e30f; int kb = 0;
        for (int k = 0; k < 32; k++) {
            float t = mu_t * omega[k] - mu[k];
            float sb = (t * t) / (omega[k] * (1.0f - omega[k]) + 1e-8f);
            if (sb > best) { best = sb; kb = k; }   // first-max, matches jnp.argmax
        }
        thr[tid] = (float)kb * 0.03125f;            // edges[k] = k/32 exact
    }
    if (tid == 63) {
        float al[4];
        float m = -1e30f;
        for (int c = 0; c < 4; c++) { al[c] = alpha_logits[c]; m = fmaxf(m, al[c]); }
        float e[4]; float s = 0.0f;
        for (int c = 0; c < 4; c++) { e[c] = expf(al[c] - m); s += e[c]; }
        float bias = 0.0f;
        for (int c = 0; c < 4; c++) {
            float alpha = e[c] / s;
            sc[c] = alpha * softplusf(cal_a[c]);
            bias += alpha * cal_b[c];
        }
        sc[4] = bias;
        float tau = 0.2f + softplusf(tau_p[0]);
        sc[5] = tau;
        sc[6] = -1.0f / tau;
    }
}

// ---------------- K2b: threshold gray -> packed bits ----------------
__global__ __launch_bounds__(256) void k_thresh(const float* __restrict__ gray,
                                                const float* __restrict__ thr,
                                                uint32_t* __restrict__ packed) {
    int b = blockIdx.y;
    int i = blockIdx.x * 256 + threadIdx.x;
    float t = thr[b];
    float v = gray[(size_t)b * IMG + i];
    unsigned long long m = __ballot(v <= t);
    if ((threadIdx.x & 63) == 0)
        *(uint64_t*)&packed[(size_t)b * 8192 + (i >> 5)] = m;
}

// ---------------- K3: bitwise morphology (erode,dilate,dilate,erode) ----------------
__global__ __launch_bounds__(256) void k_morph(const uint32_t* __restrict__ p0,
                                               uint32_t* __restrict__ pn) {
    __shared__ uint64_t s0[40], s1[40];
    int tid = threadIdx.x, b = blockIdx.z;
    int x0 = blockIdx.x * 32, y0 = blockIdx.y * 32;
    int w0 = x0 >> 5;
    const uint32_t* pb = p0 + (size_t)b * 8192;
    int xlo = (x0 == 0) ? 4 : 0;
    int xhi = (x0 == 480) ? 36 : 40;
    uint64_t mwin = kmask(xlo, xhi);

    if (tid < 40) {
        int y = y0 - 4 + tid;
        uint64_t v = 0;
        if ((unsigned)y < (unsigned)HW) {
            const uint32_t* rowp = pb + y * 16;
            uint64_t wm = (w0 > 0)  ? rowp[w0 - 1] : 0;
            uint64_t wc = rowp[w0];
            uint64_t wp = (w0 < 15) ? rowp[w0 + 1] : 0;
            v = ((wm >> 28) | (wc << 4) | (wp << 36)) & kmask(0, 40);
        }
        s0[tid] = v;
    }
    __syncthreads();
    if (tid >= 1 && tid < 39) {
        uint64_t e = ~0ull;
        for (int dq = -1; dq <= 1; dq++) {
            int q = tid + dq;
            int y = y0 - 4 + q;
            uint64_t m = ((unsigned)y < (unsigned)HW) ? mwin : 0;
            uint64_t v = s0[q] | ~m;
            e &= v & (v << 1) & (v >> 1);
        }
        s1[tid] = e;
    }
    __syncthreads();
    if (tid >= 2 && tid < 38) {
        uint64_t d = 0;
        uint64_t me = kmask(1, 39);
        for (int dq = -1; dq <= 1; dq++) {
            int q = tid + dq;
            int y = y0 - 4 + q;
            uint64_t m = ((unsigned)y < (unsigned)HW) ? (mwin & me) : 0;
            uint64_t v = s1[q] & m;
            d |= v | (v << 1) | (v >> 1);
        }
        s0[tid] = d;
    }
    __syncthreads();
    if (tid >= 3 && tid < 37) {
        uint64_t d = 0;
        uint64_t me = kmask(2, 38);
        for (int dq = -1; dq <= 1; dq++) {
            int q = tid + dq;
            int y = y0 - 4 + q;
            uint64_t m = ((unsigned)y < (unsigned)HW) ? (mwin & me) : 0;
            uint64_t v = s0[q] & m;
            d |= v | (v << 1) | (v >> 1);
        }
        s1[tid] = d;
    }
    __syncthreads();
    if (tid >= 4 && tid < 36) {
        uint64_t e = ~0ull;
        uint64_t me = kmask(3, 37);
        for (int dq = -1; dq <= 1; dq++) {
            int q = tid + dq;
            int y = y0 - 4 + q;
            uint64_t m = ((unsigned)y < (unsigned)HW) ? (mwin & me) : 0;
            uint64_t v = s1[q] | ~m;
            e &= v & (v << 1) & (v >> 1);
        }
        s0[tid] = e;
    }
    __syncthreads();
    if (tid < 32) {
        int y = y0 + tid;
        pn[(size_t)b * 8192 + y * 16 + w0] = (uint32_t)(s0[tid + 4] >> 4);
    }
}

// ---------------- K4: fused concept maps + E + expsum (sliding-window sums) ----------------
__global__ __launch_bounds__(256) void k_maps(const float* __restrict__ gray,
                                              const uint32_t* __restrict__ pn,
                                              float* __restrict__ zmap,
                                              float* __restrict__ nucf,
                                              float* __restrict__ Eout,
                                              const float* __restrict__ sc,
                                              float* __restrict__ expsum) {
    __shared__ __align__(16) char smem[30912];
    __shared__ uint64_t nrow[50], ehr[50], dilh[50], bnd[36], cell[40];
    float* gt  = (float*)smem;             // 42*43 floats
    float* st  = (float*)(smem + 7232);    // 40*41
    float* ct  = (float*)(smem + 13792);   // 40*41
    float* rs0 = (float*)(smem + 20352);   // 40*33
    float* rs1 = (float*)(smem + 25632);   // 40*33
    int* rs_n = (int*)smem;                // 40*32 (aliases gt, dead by then)
    int* rs_c = (int*)(smem + 5120);       // 40*32
    int* rs_b = (int*)(smem + 10240);      // 36*32
    float* red = (float*)(smem + 16384);   // 4 floats (aliases ct, dead by then)

    int tid = threadIdx.x, b = blockIdx.z;
    int x0 = blockIdx.x * 32, y0 = blockIdx.y * 32;
    int w0 = x0 >> 5;
    const float* gb = gray + (size_t)b * IMG;
    const uint32_t* pb = pn + (size_t)b * 8192;
    int xlo = (x0 == 0) ? 9 : 0;
    int xhi = (x0 == 480) ? 41 : 50;
    uint64_t mwin = kmask(xlo, xhi);

    // ---- A: loads ----
    for (int i = tid; i < 42 * 42; i += 256) {
        int ly = i / 42, lx = i % 42;
        int gy = y0 + ly - 5, gx = x0 + lx - 5;
        gt[ly * 43 + lx] = (gy >= 0 && gy < HW && gx >= 0 && gx < HW) ? gb[gy * HW + gx] : 0.0f;
    }
    if (tid < 50) {
        int y = y0 - 9 + tid;
        uint64_t v = 0;
        if ((unsigned)y < (unsigned)HW) {
            const uint32_t* rowp = pb + y * 16;
            uint64_t wm = (w0 > 0)  ? rowp[w0 - 1] : 0;
            uint64_t wc = rowp[w0];
            uint64_t wp = (w0 < 15) ? rowp[w0 + 1] : 0;
            v = ((wm >> 23) | (wc << 9) | (wp << 41)) & kmask(0, 50);
        }
        nrow[tid] = v;
    }
    __syncthreads();

    // ---- B: bit dilate/erode rows + Sobel ----
    if (tid < 50) {
        uint64_t v = nrow[tid];
        uint64_t d = v | (v << 1) | (v >> 1);
        d = d | (d << 2) | (d >> 2);
        d = d | (d << 2) | (d >> 2);
        dilh[tid] = d;
    }
    if (tid >= 6 && tid < 44) {
        int y = y0 - 9 + tid;
        uint64_t m = ((unsigned)y < (unsigned)HW) ? mwin : 0;
        uint64_t v = nrow[tid] | ~m;
        ehr[tid] = v & (v << 1) & (v >> 1);
    }
    for (int i = tid; i < 1600; i += 256) {
        int ly = i / 40, lx = i % 40;
        int gy = y0 + ly - 4, gx = x0 + lx - 4;
        float s = 0.0f, c = 0.0f;
        if (gy >= 0 && gy < HW && gx >= 0 && gx < HW) {
            float a00 = gt[ly * 43 + lx],       a01 = gt[ly * 43 + lx + 1],       a02 = gt[ly * 43 + lx + 2];
            float a10 = gt[(ly + 1) * 43 + lx],                                   a12 = gt[(ly + 1) * 43 + lx + 2];
            float a20 = gt[(ly + 2) * 43 + lx], a21 = gt[(ly + 2) * 43 + lx + 1], a22 = gt[(ly + 2) * 43 + lx + 2];
            float gxv = (a00 - a02) + 2.0f * (a10 - a12) + (a20 - a22);
            float gyv = (a00 + 2.0f * a01 + a02) - (a20 + 2.0f * a21 + a22);
            float r2 = gxv * gxv + gyv * gyv;
            if (r2 > 0.0f) { float ir = frsq(r2); s = gyv * ir; c = gxv * ir; }
            else { s = 0.0f; c = 1.0f; }
        }
        st[ly * 41 + lx] = s; ct[ly * 41 + lx] = c;
    }
    __syncthreads();

    // ---- C: bit phase 2 + sin/cos 9-window row sums (4 outputs/thread, sliding) ----
    if (tid < 36) {
        int r = tid + 7;
        uint64_t er = ehr[r - 1] & ehr[r] & ehr[r + 1];
        bnd[tid] = nrow[r] & ~er;
    }
    if (tid < 40) {
        int r = tid + 5;
        int y = y0 - 4 + tid;
        uint64_t c = 0;
        for (int d = -5; d <= 5; d++) c |= dilh[r + d];
        uint64_t m = ((unsigned)y < (unsigned)HW) ? mwin : 0;
        cell[tid] = c & m;
    }
    for (int i = tid; i < 320; i += 256) {
        int ly = i >> 3, c0 = (i & 7) << 2;
        int base = ly * 41 + c0;
        float sa[12], ca[12];
        #pragma unroll
        for (int j = 0; j < 12; j++) { sa[j] = st[base + j]; ca[j] = ct[base + j]; }
        float ss = sa[0]+sa[1]+sa[2]+sa[3]+sa[4]+sa[5]+sa[6]+sa[7]+sa[8];
        float cs = ca[0]+ca[1]+ca[2]+ca[3]+ca[4]+ca[5]+ca[6]+ca[7]+ca[8];
        int ob = ly * 33 + c0;
        rs0[ob] = ss; rs1[ob] = cs;
        #pragma unroll
        for (int q = 1; q < 4; q++) {
            ss += sa[8 + q] - sa[q - 1];
            cs += ca[8 + q] - ca[q - 1];
            rs0[ob + q] = ss; rs1[ob + q] = cs;
        }
    }
    __syncthreads();

    // ---- D: z1 column sums (4 consecutive rows/thread, sliding) ----
    int p = tid & 31, py0 = (tid >> 5) << 2;
    int gx = x0 + p;
    float cntx = (float)(min(gx + 4, HW - 1) - max(gx - 4, 0) + 1);
    float z1v[4], z3v[4];
    {
        float s[12], c[12];
        #pragma unroll
        for (int j = 0; j < 12; j++) { s[j] = rs0[(py0 + j) * 33 + p]; c[j] = rs1[(py0 + j) * 33 + p]; }
        float ss = s[0]+s[1]+s[2]+s[3]+s[4]+s[5]+s[6]+s[7]+s[8];
        float cs = c[0]+c[1]+c[2]+c[3]+c[4]+c[5]+c[6]+c[7]+c[8];
        #pragma unroll
        for (int q = 0; q < 4; q++) {
            int gy = y0 + py0 + q;
            float cnty = (float)(min(gy + 4, HW - 1) - max(gy - 4, 0) + 1);
            float iden = frcp(cnty * cntx + 1e-6f);
            float ms = ss * iden, mc = cs * iden;
            z1v[q] = 1.0f - sqrtf(ms * ms + mc * mc + 1e-6f);
            if (q < 3) { ss += s[9 + q] - s[q]; cs += c[9 + q] - c[q]; }
        }
    }
    __syncthreads();

    // ---- E: gray / gray^2 9-window row sums (reuse rs0/rs1) ----
    for (int i = tid; i < 320; i += 256) {
        int ly = i >> 3, c0 = (i & 7) << 2;
        int base = (ly + 1) * 43 + c0 + 1;
        float v[12];
        #pragma unroll
        for (int j = 0; j < 12; j++) v[j] = gt[base + j];
        float gs = v[0]+v[1]+v[2]+v[3]+v[4]+v[5]+v[6]+v[7]+v[8];
        float g2 = v[0]*v[0]+v[1]*v[1]+v[2]*v[2]+v[3]*v[3]+v[4]*v[4]+v[5]*v[5]+v[6]*v[6]+v[7]*v[7]+v[8]*v[8];
        int ob = ly * 33 + c0;
        rs0[ob] = gs; rs1[ob] = g2;
        #pragma unroll
        for (int q = 1; q < 4; q++) {
            gs += v[8 + q] - v[q - 1];
            g2 += v[8 + q] * v[8 + q] - v[q - 1] * v[q - 1];
            rs0[ob + q] = gs; rs1[ob + q] = g2;
        }
    }
    __syncthreads();

    // ---- F: z3 column sums ----
    {
        float s[12], c[12];
        #pragma unroll
        for (int j = 0; j < 12; j++) { s[j] = rs0[(py0 + j) * 33 + p]; c[j] = rs1[(py0 + j) * 33 + p]; }
        float gs = s[0]+s[1]+s[2]+s[3]+s[4]+s[5]+s[6]+s[7]+s[8];
        float g2 = c[0]+c[1]+c[2]+c[3]+c[4]+c[5]+c[6]+c[7]+c[8];
        #pragma unroll
        for (int q = 0; q < 4; q++) {
            int gy = y0 + py0 + q;
            float cnty = (float)(min(gy + 4, HW - 1) - max(gy - 4, 0) + 1);
            float iden = frcp(cnty * cntx + 1e-6f);
            float g1 = gs * iden, gq = g2 * iden;
            z3v[q] = flog1p(fmaxf(gq - g1 * g1, 0.0f));
            if (q < 3) { gs += s[9 + q] - s[q]; g2 += c[9 + q] - c[q]; }
        }
    }
    __syncthreads();   // float LDS dead; int arrays may alias

    // ---- G: popcount row windows ----
    for (int i = tid; i < 40 * 32; i += 256) {
        int rr = i >> 5, pp = i & 31;
        rs_n[rr * 32 + pp] = __popcll((nrow[rr + 5] >> (pp + 5)) & 0x1FFull);
        rs_c[rr * 32 + pp] = __popcll((cell[rr]     >> (pp + 5)) & 0x1FFull);
    }
    for (int i = tid; i < 36 * 32; i += 256) {
        int rr = i >> 5, pp = i & 31;
        rs_b[rr * 32 + pp] = __popcll((bnd[rr] >> (pp + 7)) & 0x1Full);
    }
    __syncthreads();

    // ---- H: epilogue (4 consecutive rows/thread, sliding int col sums) ----
    float w0f = sc[0], w1f = sc[1], w2f = sc[2], w3f = sc[3], bias = sc[4], ntau = sc[6];
    float* z0p = zmap + ((size_t)b * 4 + 0) * IMG;
    float* z1p = zmap + ((size_t)b * 4 + 1) * IMG;
    float* z2p = zmap + ((size_t)b * 4 + 2) * IMG;
    float* z3p = zmap + ((size_t)b * 4 + 3) * IMG;
    float* Ep  = Eout + (size_t)b * IMG;
    float* np  = nucf + (size_t)b * IMG;
    float acc = 0.0f;
    {
        int nn[12], cc[12], bb8[8];
        #pragma unroll
        for (int j = 0; j < 12; j++) { nn[j] = rs_n[(py0 + j) * 32 + p]; cc[j] = rs_c[(py0 + j) * 32 + p]; }
        #pragma unroll
        for (int j = 0; j < 8; j++) bb8[j] = rs_b[(py0 + j) * 32 + p];
        int An = nn[0]+nn[1]+nn[2]+nn[3]+nn[4]+nn[5]+nn[6]+nn[7]+nn[8];
        int Ac = cc[0]+cc[1]+cc[2]+cc[3]+cc[4]+cc[5]+cc[6]+cc[7]+cc[8];
        int db = bb8[0]+bb8[1]+bb8[2]+bb8[3]+bb8[4];
        int kk = p + 9;
        #pragma unroll
        for (int q = 0; q < 4; q++) {
            int py = py0 + q;
            int r = py + 9;
            uint64_t rowc = nrow[r];
            int cbit = (int)((rowc >> kk) & 1);
            int nb4  = (int)((nrow[r - 1] >> kk) & 1) + (int)((nrow[r + 1] >> kk) & 1)
                     + (int)((rowc >> (kk - 1)) & 1) + (int)((rowc >> (kk + 1)) & 1);
            int lap = nb4 - 4 * cbit; lap = lap < 0 ? -lap : lap;
            int bc  = (int)((bnd[py + 2] >> kk) & 1);
            float rough = (float)(lap * bc) * frcp((float)db + 1e-6f);
            float z2 = (float)An * frcp(fmaxf((float)(Ac - An), 1.0f));
            float z0s = flog1p(fmaxf(rough, 0.0f));
            float z1s = fminf(fmaxf(z1v[q], 0.0f), 1.0f);
            float z2s = flog1p(fmaxf(z2, 0.0f));
            float z3s = fminf(fmaxf(z3v[q], 0.0f), MLOG32f);
            float E = w0f * z0s + w1f * z1s + w2f * z2s + w3f * z3s + bias;
            int gy = y0 + py;
            size_t o = (size_t)gy * HW + x0 + p;
            z0p[o] = rough;
            z1p[o] = z1v[q];
            z2p[o] = z2;
            z3p[o] = z3v[q];
            Ep[o]  = E;
            np[o]  = (float)cbit;
            acc += __expf(E * ntau);
            if (q < 3) {
                An += nn[9 + q] - nn[q];
                Ac += cc[9 + q] - cc[q];
                db += bb8[5 + q] - bb8[q];
            }
        }
    }
    for (int off = 32; off > 0; off >>= 1) acc += __shfl_down(acc, off, 64);
    if ((tid & 63) == 0) red[tid >> 6] = acc;
    __syncthreads();
    if (tid == 0) atomicAdd(&expsum[b], red[0] + red[1] + red[2] + red[3]);
}

// ---------------- K5: A = exp(-E/tau) / S ----------------
__global__ __launch_bounds__(256) void k_softmaxA(const float* __restrict__ E,
                                                  float* __restrict__ A,
                                                  const float* __restrict__ sc,
                                                  const float* __restrict__ expsum) {
    int b = blockIdx.y;
    int i = blockIdx.x * 256 + threadIdx.x;
    float ntau = sc[6];
    float invS = 1.0f / expsum[b];
    const float4* Ep = (const float4*)(E + (size_t)b * IMG);
    float4* Ap = (float4*)(A + (size_t)b * IMG);
    float4 e = Ep[i];
    float4 o;
    o.x = __expf(e.x * ntau) * invS;
    o.y = __expf(e.y * ntau) * invS;
    o.z = __expf(e.z * ntau) * invS;
    o.w = __expf(e.w * ntau) * invS;
    Ap[i] = o;
}

extern "C" void kernel_launch(void* const* d_in, const int* in_sizes, int n_in,
                              void* d_out, int out_size, void* d_ws, size_t ws_size,
                              hipStream_t stream) {
    const float* img   = (const float*)d_in[0];
    const float* cal_a = (const float*)d_in[1];
    const float* cal_b = (const float*)d_in[2];
    const float* alpha = (const float*)d_in[3];
    const float* tau_p = (const float*)d_in[4];
    int B = in_sizes[0] / (3 * IMG);

    float* out  = (float*)d_out;
    float* A    = out;                          // (B,1,H,W)
    float* zmap = out + (size_t)B * IMG;        // (B,4,H,W)
    float* nuc  = out + (size_t)B * IMG * 5;    // (B,1,H,W)
    float* E    = out + (size_t)B * IMG * 6;    // (B,1,H,W)
    float* gray = A;                            // A region doubles as gray scratch

    // ws layout: hist(B*32 int) | expsum(B) | thr(B) | sc(8) | packed0 | packedN
    int*      hist    = (int*)d_ws;
    float*    expsum  = (float*)d_ws + B * 32;
    float*    thr     = expsum + B;
    float*    sc      = thr + B;
    uint32_t* packed0 = (uint32_t*)d_ws + 1024;
    uint32_t* packedN = packed0 + (size_t)B * 8192;

    hipMemsetAsync(d_ws, 0, (size_t)(B * 32 + B) * 4, stream);   // hist + expsum
    k_gray_hist<<<dim3(IMG / 1024, B), 256, 0, stream>>>(img, gray, hist);
    k_otsu_sc<<<1, 64, 0, stream>>>(hist, cal_a, cal_b, alpha, tau_p, thr, sc, B);
    k_thresh<<<dim3(IMG / 256, B), 256, 0, stream>>>(gray, thr, packed0);
    dim3 tg(HW / 32, HW / 32, B);
    k_morph<<<tg, 256, 0, stream>>>(packed0, packedN);
    k_maps<<<tg, 256, 0, stream>>>(gray, packedN, zmap, nuc, E, sc, expsum);
    k_softmaxA<<<dim3(IMG / 1024, B), 256, 0, stream>>>(E, A, sc, expsum);
}